// Round 1
// baseline (148.456 us; speedup 1.0000x reference)
//
#include <hip/hip_runtime.h>

#define Tn   256
#define BWn  150
#define BIGF 1.0e8f

// One block per (sdtw_call, batch) pair: 4*128 = 512 blocks, 256 threads.
// Thread t owns matrix row i = t+1 across the whole anti-diagonal wavefront.
// y sequence staged in LDS; 3 rotating diagonals in LDS; x row in registers.
__global__ __launch_bounds__(256) void sdtw_kernel(
    const float* __restrict__ pred, const float* __restrict__ gt,
    const int* __restrict__ perm_gen, const int* __restrict__ perm_real,
    float* __restrict__ out) {
  const int blk = blockIdx.x;
  const int c = blk >> 7;        // which of the 4 sdtw calls
  const int b = blk & 127;       // batch element

  const float* x;
  const float* y;
  if (c == 0)      { x = pred + b * Tn * 3; y = gt   + b * Tn * 3; }
  else if (c == 1) { x = gt   + b * Tn * 3; y = pred + b * Tn * 3; }
  else if (c == 2) { x = pred + b * Tn * 3; y = pred + perm_gen[b]  * Tn * 3; }
  else             { x = gt   + b * Tn * 3; y = gt   + perm_real[b] * Tn * 3; }

  __shared__ float ylds[Tn * 3];
  __shared__ float rbuf[3][Tn + 1];

  const int t = threadIdx.x;

  // stage y (3 KB) into LDS, coalesced
  for (int k = t; k < Tn * 3; k += 256) ylds[k] = y[k];

  // this thread's x row (i-1 = t), held in registers for all 511 steps
  const float x0 = x[t * 3 + 0];
  const float x1 = x[t * 3 + 1];
  const float x2 = x[t * 3 + 2];

  // init: rbuf[0] = diagonal d=0 (r[0,0]=0, rest BIG); rbuf[1] = diagonal d=1 (all BIG)
  rbuf[0][t + 1] = BIGF;
  rbuf[1][t + 1] = BIGF;
  if (t == 0) { rbuf[0][0] = 0.0f; rbuf[1][0] = BIGF; }
  __syncthreads();

  const int i = t + 1;           // 1..256
  int cur = 2, p1 = 1, p2 = 0;   // buffer indices for d, d-1, d-2
  float rlast = BIGF;

  #pragma unroll 1
  for (int d = 2; d <= 2 * Tn; ++d) {
    const int j = d - i;
    const int dij = i - j;
    const bool valid = (j >= 1) & (j <= Tn) & (dij <= BWn) & (dij >= -BWn);

    // focal-Manhattan cost, clamped y index for out-of-range (invalid) lanes
    int cj = j - 1;
    cj = cj < 0 ? 0 : (cj > Tn - 1 ? Tn - 1 : cj);
    const float y0 = ylds[cj * 3 + 0];
    const float y1 = ylds[cj * 3 + 1];
    const float y2 = ylds[cj * 3 + 2];
    const float dl1 = fabsf(x0 - y0) + fabsf(x1 - y1) + fabsf(x2 - y2);
    const float om  = 1.0f - __expf(-dl1);
    const float cost = 0.6f * om * om * dl1;   // FOCAL_ALPHA * (1-e^-d)^2 * d

    // soft-min over {up, left, diag}, gamma = 0.1 (stable: shift by min)
    const float up   = rbuf[p1][i - 1];
    const float left = rbuf[p1][i];
    const float diag = rbuf[p2][i - 1];
    const float m = fminf(fminf(up, left), diag);
    const float s = __expf((m - up)   * 10.0f)
                  + __expf((m - left) * 10.0f)
                  + __expf((m - diag) * 10.0f);
    const float smin = m - 0.1f * __logf(s);

    const float r = valid ? (cost + smin) : BIGF;
    rbuf[cur][i] = r;
    if (t == 0) rbuf[cur][0] = BIGF;   // border cell i=0 of this diagonal
    rlast = r;
    __syncthreads();

    // rotate buffers: cur -> p1, p1 -> p2, p2 -> cur
    const int tmp = p2;
    p2 = p1;
    p1 = cur;
    cur = tmp;
  }

  // r[T,T] lives at i=256 (t=255) on diagonal d=2T
  if (t == Tn - 1) out[blk] = rlast;
}

// One block per batch element: KL term, gt transition count, soft transition count.
__global__ __launch_bounds__(256) void stats_kernel(
    const float* __restrict__ pred, const float* __restrict__ gt,
    const float* __restrict__ mu, const float* __restrict__ lv,
    const float* __restrict__ ptc, float* __restrict__ ws) {
  const int b = blockIdx.x;
  const int t = threadIdx.x;
  __shared__ float red[256];
  __shared__ float gtr_sh;

  // KL: -0.5 * sum_L (1 + lv - mu^2 - exp(lv)), free bits, relu
  float v = 0.0f;
  if (t < 128) {
    const float m = mu[b * 128 + t];
    const float l = lv[b * 128 + t];
    v = 1.0f + l - m * m - __expf(l);
  }
  red[t] = v; __syncthreads();
  for (int s = 128; s > 0; s >>= 1) { if (t < s) red[t] += red[t + s]; __syncthreads(); }
  if (t == 0) {
    const float klb = -0.5f * red[0];
    ws[512 + b] = fmaxf(klb - 0.5f, 0.0f);
  }
  __syncthreads();

  // gt_trans: sum |gt[b,t+1,2] - gt[b,t,2]|
  float g = 0.0f;
  if (t < Tn - 1)
    g = fabsf(gt[(b * Tn + t + 1) * 3 + 2] - gt[(b * Tn + t) * 3 + 2]);
  red[t] = g; __syncthreads();
  for (int s = 128; s > 0; s >>= 1) { if (t < s) red[t] += red[t + s]; __syncthreads(); }
  if (t == 0) gtr_sh = red[0];
  __syncthreads();
  const float gtr = gtr_sh;

  // soft transitions of pred touch channel: sigmoid((p-0.5)*10) diffs
  float p = 0.0f;
  if (t < Tn - 1) {
    const float z0 = (pred[(b * Tn + t) * 3 + 2]     - 0.5f) * 10.0f;
    const float z1 = (pred[(b * Tn + t + 1) * 3 + 2] - 0.5f) * 10.0f;
    const float s0 = 1.0f / (1.0f + __expf(-z0));
    const float s1 = 1.0f / (1.0f + __expf(-z1));
    p = fabsf(s1 - s0);
  }
  red[t] = p; __syncthreads();
  for (int s = 128; s > 0; s >>= 1) { if (t < s) red[t] += red[t + s]; __syncthreads(); }
  if (t == 0) {
    const float pts = red[0];
    const float d1 = ptc[b] - gtr;
    ws[640 + b] = d1 * d1;        // aux per-b
    const float d2 = pts - gtr;
    ws[768 + b] = d2 * d2;        // trans_reg per-b
  }
}

// Single block: reduce the 7 per-b arrays and emit (total, nag, kl, aux, trans_reg).
__global__ __launch_bounds__(128) void final_kernel(
    const float* __restrict__ ws, float* __restrict__ out) {
  const int t = threadIdx.x;   // 128 threads
  __shared__ float red[128];
  float sums[7];
  #pragma unroll
  for (int q = 0; q < 7; ++q) {
    red[t] = ws[q * 128 + t];
    __syncthreads();
    for (int s = 64; s > 0; s >>= 1) { if (t < s) red[t] += red[t + s]; __syncthreads(); }
    if (t == 0) sums[q] = red[0];
    __syncthreads();
  }
  if (t == 0) {
    const float inv = 1.0f / 128.0f;
    const float sim   = (sums[0] + sums[1]) * inv;
    const float dgen  = sums[2] * inv;
    const float dreal = sums[3] * inv;
    const float nag   = sim + fabsf(dgen - dreal);
    const float kl    = sums[4] * inv;
    const float aux   = sums[5] * inv;
    const float trans = sums[6] * inv;
    const float total = nag + 1.0f * kl + 0.1f * aux + 0.5f * trans;
    out[0] = total;
    out[1] = nag;
    out[2] = kl;
    out[3] = aux;
    out[4] = trans;
  }
}

extern "C" void kernel_launch(void* const* d_in, const int* in_sizes, int n_in,
                              void* d_out, int out_size, void* d_ws, size_t ws_size,
                              hipStream_t stream) {
  const float* pred = (const float*)d_in[0];   // (128,256,3)
  const float* gt   = (const float*)d_in[1];   // (128,256,3)
  const float* mu   = (const float*)d_in[2];   // (128,128)
  const float* lv   = (const float*)d_in[3];   // (128,128)
  const float* ptc  = (const float*)d_in[4];   // (128,1)
  const int*   pg   = (const int*)d_in[5];     // (128,)
  const int*   pr   = (const int*)d_in[6];     // (128,)
  float* ws  = (float*)d_ws;   // [0..511] sdtw, [512..639] kl, [640..767] aux, [768..895] trans
  float* out = (float*)d_out;  // 5 floats

  sdtw_kernel<<<512, 256, 0, stream>>>(pred, gt, pg, pr, ws);
  stats_kernel<<<128, 256, 0, stream>>>(pred, gt, mu, lv, ptc, ws);
  final_kernel<<<1, 128, 0, stream>>>(ws, out);
}

// Round 2
// 139.947 us; speedup vs baseline: 1.0608x; 1.0608x over previous
//
#include <hip/hip_runtime.h>

#define Tn 256
// Recurrence is carried as u = -(10*log2e) * r  (r = DTW partial cost).
// softmin identity: u_new = max3(u) + log2(sum exp2(u_i - max3)) - 14.4269504*cost
// with cost = 0.6*om^2*dl1 folded as -8.65617024*om^2*dl1.
#define UBIG (-1.442695e9f)   // u-image of BIG=1e8

__global__ __launch_bounds__(256) void sdtw_kernel(
    const float* __restrict__ pred, const float* __restrict__ gt,
    const int* __restrict__ perm_gen, const int* __restrict__ perm_real,
    float* __restrict__ out) {
  const int blk = blockIdx.x;
  const int c = blk >> 7;        // which of the 4 sdtw calls
  const int b = blk & 127;       // batch element

  const float* x;
  const float* y;
  if (c == 0)      { x = pred + b * Tn * 3; y = gt   + b * Tn * 3; }
  else if (c == 1) { x = gt   + b * Tn * 3; y = pred + b * Tn * 3; }
  else if (c == 2) { x = pred + b * Tn * 3; y = pred + perm_gen[b]  * Tn * 3; }
  else             { x = gt   + b * Tn * 3; y = gt   + perm_real[b] * Tn * 3; }

  __shared__ float ylds[3][Tn];      // SoA: one vaddr, imm offsets 0/1024/2048
  __shared__ float rbuf[3][Tn + 1];  // 3 rotating anti-diagonals (u-scaled)

  const int t = threadIdx.x;

  // stage y (3 KB) into LDS, transposed to SoA
  for (int k = t; k < Tn * 3; k += 256) ylds[k % 3][k / 3] = y[k];

  // this thread's x row (i-1 = t), in registers for all steps
  const float x0 = x[t * 3 + 0];
  const float x1 = x[t * 3 + 1];
  const float x2 = x[t * 3 + 2];

  const int i = t + 1;               // matrix row, 1..256

  // valid window per thread: d in [lo, hi]
  //   j>=1 -> d>=i+1 ; j<=T -> d<=i+T ; |2i-d|<=150
  const int lo = max(i + 1, 2 * i - 150);
  const int hi = min(i + Tn, 2 * i + 150);
  const unsigned span = (unsigned)(hi - lo);

  // incremental per-step counters (incremented at top of each STEP)
  int vcj = -t - 1;                  // becomes d - t - 2 (= j-1) after first ++
  int vdl = 1 - lo;                  // becomes d - lo after first ++

  // init: rbuf[0] = diag d=0 (u[0,0]=0, rest UBIG); rbuf[1] = diag d=1 (UBIG)
  rbuf[0][i] = UBIG;
  rbuf[1][i] = UBIG;
  if (t == 0) { rbuf[0][0] = 0.0f; rbuf[1][0] = UBIG; rbuf[2][0] = UBIG; }
  __syncthreads();

#define STEP(CUR, P1, P2) do {                                          \
    vcj += 1; vdl += 1;                                                 \
    const int cj = vcj & 255;                                           \
    const float yy0 = ylds[0][cj];                                      \
    const float yy1 = ylds[1][cj];                                      \
    const float yy2 = ylds[2][cj];                                      \
    const float dl1 = fabsf(x0 - yy0) + fabsf(x1 - yy1) + fabsf(x2 - yy2); \
    const float ex  = exp2f(dl1 * -1.44269504f);                        \
    const float om  = 1.0f - ex;                                        \
    const float up  = rbuf[P1][i - 1];                                  \
    const float lf  = rbuf[P1][i];                                      \
    const float dg  = rbuf[P2][i - 1];                                  \
    const float mx  = fmaxf(fmaxf(up, lf), dg);                         \
    const float s   = exp2f(up - mx) + exp2f(lf - mx) + exp2f(dg - mx); \
    float un = fmaf(om * om * dl1, -8.65617024f, mx) + __log2f(s);      \
    un = ((unsigned)vdl <= span) ? un : UBIG;                           \
    rbuf[CUR][i] = un;                                                  \
    __syncthreads();                                                    \
  } while (0)

  STEP(2, 1, 0);                       // d = 2
  if (t == 0) rbuf[0][0] = UBIG;       // one-time border fix: r[0][j>=1] = BIG
  STEP(0, 2, 1);                       // d = 3
  STEP(1, 0, 2);                       // d = 4
  #pragma unroll 1
  for (int k = 0; k < 169; ++k) {      // d = 5 .. 511
    STEP(2, 1, 0);
    STEP(0, 2, 1);
    STEP(1, 0, 2);
  }
  STEP(2, 1, 0);                       // d = 512

  // r[T,T] = u / -14.4269504
  if (t == Tn - 1) out[blk] = rbuf[2][Tn] * -0.0693147181f;
#undef STEP
}

// One block per batch element: KL term, gt transition count, soft transition count.
__global__ __launch_bounds__(256) void stats_kernel(
    const float* __restrict__ pred, const float* __restrict__ gt,
    const float* __restrict__ mu, const float* __restrict__ lv,
    const float* __restrict__ ptc, float* __restrict__ ws) {
  const int b = blockIdx.x;
  const int t = threadIdx.x;
  __shared__ float red[256];
  __shared__ float gtr_sh;

  // KL: -0.5 * sum_L (1 + lv - mu^2 - exp(lv)), free bits, relu
  float v = 0.0f;
  if (t < 128) {
    const float m = mu[b * 128 + t];
    const float l = lv[b * 128 + t];
    v = 1.0f + l - m * m - __expf(l);
  }
  red[t] = v; __syncthreads();
  for (int s = 128; s > 0; s >>= 1) { if (t < s) red[t] += red[t + s]; __syncthreads(); }
  if (t == 0) {
    const float klb = -0.5f * red[0];
    ws[512 + b] = fmaxf(klb - 0.5f, 0.0f);
  }
  __syncthreads();

  // gt_trans: sum |gt[b,t+1,2] - gt[b,t,2]|
  float g = 0.0f;
  if (t < Tn - 1)
    g = fabsf(gt[(b * Tn + t + 1) * 3 + 2] - gt[(b * Tn + t) * 3 + 2]);
  red[t] = g; __syncthreads();
  for (int s = 128; s > 0; s >>= 1) { if (t < s) red[t] += red[t + s]; __syncthreads(); }
  if (t == 0) gtr_sh = red[0];
  __syncthreads();
  const float gtr = gtr_sh;

  // soft transitions of pred touch channel: sigmoid((p-0.5)*10) diffs
  float p = 0.0f;
  if (t < Tn - 1) {
    const float z0 = (pred[(b * Tn + t) * 3 + 2]     - 0.5f) * 10.0f;
    const float z1 = (pred[(b * Tn + t + 1) * 3 + 2] - 0.5f) * 10.0f;
    const float s0 = 1.0f / (1.0f + __expf(-z0));
    const float s1 = 1.0f / (1.0f + __expf(-z1));
    p = fabsf(s1 - s0);
  }
  red[t] = p; __syncthreads();
  for (int s = 128; s > 0; s >>= 1) { if (t < s) red[t] += red[t + s]; __syncthreads(); }
  if (t == 0) {
    const float pts = red[0];
    const float d1 = ptc[b] - gtr;
    ws[640 + b] = d1 * d1;        // aux per-b
    const float d2 = pts - gtr;
    ws[768 + b] = d2 * d2;        // trans_reg per-b
  }
}

// Single block: reduce the 7 per-b arrays and emit (total, nag, kl, aux, trans_reg).
__global__ __launch_bounds__(128) void final_kernel(
    const float* __restrict__ ws, float* __restrict__ out) {
  const int t = threadIdx.x;   // 128 threads
  __shared__ float red[128];
  float sums[7];
  #pragma unroll
  for (int q = 0; q < 7; ++q) {
    red[t] = ws[q * 128 + t];
    __syncthreads();
    for (int s = 64; s > 0; s >>= 1) { if (t < s) red[t] += red[t + s]; __syncthreads(); }
    if (t == 0) sums[q] = red[0];
    __syncthreads();
  }
  if (t == 0) {
    const float inv = 1.0f / 128.0f;
    const float sim   = (sums[0] + sums[1]) * inv;
    const float dgen  = sums[2] * inv;
    const float dreal = sums[3] * inv;
    const float nag   = sim + fabsf(dgen - dreal);
    const float kl    = sums[4] * inv;
    const float aux   = sums[5] * inv;
    const float trans = sums[6] * inv;
    const float total = nag + 1.0f * kl + 0.1f * aux + 0.5f * trans;
    out[0] = total;
    out[1] = nag;
    out[2] = kl;
    out[3] = aux;
    out[4] = trans;
  }
}

extern "C" void kernel_launch(void* const* d_in, const int* in_sizes, int n_in,
                              void* d_out, int out_size, void* d_ws, size_t ws_size,
                              hipStream_t stream) {
  const float* pred = (const float*)d_in[0];   // (128,256,3)
  const float* gt   = (const float*)d_in[1];   // (128,256,3)
  const float* mu   = (const float*)d_in[2];   // (128,128)
  const float* lv   = (const float*)d_in[3];   // (128,128)
  const float* ptc  = (const float*)d_in[4];   // (128,1)
  const int*   pg   = (const int*)d_in[5];     // (128,)
  const int*   pr   = (const int*)d_in[6];     // (128,)
  float* ws  = (float*)d_ws;   // [0..511] sdtw, [512..639] kl, [640..767] aux, [768..895] trans
  float* out = (float*)d_out;  // 5 floats

  sdtw_kernel<<<512, 256, 0, stream>>>(pred, gt, pg, pr, ws);
  stats_kernel<<<128, 256, 0, stream>>>(pred, gt, mu, lv, ptc, ws);
  final_kernel<<<1, 128, 0, stream>>>(ws, out);
}

// Round 3
// 111.531 us; speedup vs baseline: 1.3311x; 1.2548x over previous
//
#include <hip/hip_runtime.h>

#define Tn 256
// Recurrence is carried as u = -(10*log2e) * r  (r = DTW partial cost).
// softmin identity: u_new = max3(u) + log2(sum exp2(u_i - max3)) - 14.4269504*cost
// with cost = 0.6*om^2*dl1 folded as -8.65617024*om^2*dl1.
#define UBIG (-1.442695e9f)   // u-image of BIG=1e8
#define E2(v) __builtin_amdgcn_exp2f(v)   // native v_exp_f32 (2^x)
#define LG2(v) __builtin_amdgcn_logf(v)   // native v_log_f32 (log2 x)

__global__ __launch_bounds__(256) void sdtw_kernel(
    const float* __restrict__ pred, const float* __restrict__ gt,
    const int* __restrict__ perm_gen, const int* __restrict__ perm_real,
    float* __restrict__ out) {
  const int blk = blockIdx.x;
  const int c = blk >> 7;        // which of the 4 sdtw calls
  const int b = blk & 127;       // batch element

  const float* x;
  const float* y;
  if (c == 0)      { x = pred + b * Tn * 3; y = gt   + b * Tn * 3; }
  else if (c == 1) { x = gt   + b * Tn * 3; y = pred + b * Tn * 3; }
  else if (c == 2) { x = pred + b * Tn * 3; y = pred + perm_gen[b]  * Tn * 3; }
  else             { x = gt   + b * Tn * 3; y = gt   + perm_real[b] * Tn * 3; }

  __shared__ float ylds[Tn][3];      // AoS, same layout as global: flat copy
  __shared__ float rbuf[Tn + 1][3];  // interleaved: row i holds {buf0,buf1,buf2}

  const int t = threadIdx.x;

  // stage y (3 KB) into LDS, coalesced flat copy
  for (int k = t; k < Tn * 3; k += 256) (&ylds[0][0])[k] = y[k];

  // this thread's x row (i-1 = t), in registers for all steps
  const float x0 = x[t * 3 + 0];
  const float x1 = x[t * 3 + 1];
  const float x2 = x[t * 3 + 2];

  const int i = t + 1;               // matrix row, 1..256

  // valid window per thread: d in [lo, hi]
  const int lo = max(i + 1, 2 * i - 150);
  const int hi = min(i + Tn, 2 * i + 150);
  const unsigned span = (unsigned)(hi - lo);

  // incremental per-step counters (incremented at top of each STEP)
  int vcj = -t - 1;                  // becomes j-1 = d-t-2 after first ++
  int vdl = 1 - lo;                  // becomes d - lo after first ++

  // init: buf0 = diag d=0 (u[0,0]=0, rest UBIG); buf1 = diag d=1 (all UBIG)
  rbuf[i][0] = UBIG;
  rbuf[i][1] = UBIG;
  if (t == 0) { rbuf[0][0] = 0.0f; rbuf[0][1] = UBIG; rbuf[0][2] = UBIG; }
  float lf = UBIG;                   // left = this thread's own previous value
  __syncthreads();

#define STEP(CUR, P1, P2) do {                                          \
    vcj += 1; vdl += 1;                                                 \
    const int cj = vcj & 255;                                           \
    const float yy0 = ylds[cj][0];                                      \
    const float yy1 = ylds[cj][1];                                      \
    const float yy2 = ylds[cj][2];                                      \
    const float dl1 = fabsf(x0 - yy0) + fabsf(x1 - yy1) + fabsf(x2 - yy2); \
    const float ex  = E2(dl1 * -1.44269504f);                           \
    const float om  = 1.0f - ex;                                        \
    const float up  = rbuf[i - 1][P1];                                  \
    const float dg  = rbuf[i - 1][P2];                                  \
    const float mx  = fmaxf(fmaxf(up, lf), dg);                         \
    const float s   = E2(up - mx) + E2(lf - mx) + E2(dg - mx);          \
    float un = fmaf(om * om * dl1, -8.65617024f, mx) + LG2(s);          \
    un = ((unsigned)vdl <= span) ? un : UBIG;                           \
    rbuf[i][CUR] = un;                                                  \
    lf = un;                                                            \
    __syncthreads();                                                    \
  } while (0)

  STEP(2, 1, 0);                       // d = 2
  if (t == 0) rbuf[0][0] = UBIG;       // one-time border fix: r[d>=1][i=0] = BIG
  STEP(0, 2, 1);                       // d = 3
  STEP(1, 0, 2);                       // d = 4
  #pragma unroll 1
  for (int k = 0; k < 169; ++k) {      // d = 5 .. 511
    STEP(2, 1, 0);
    STEP(0, 2, 1);
    STEP(1, 0, 2);
  }
  STEP(2, 1, 0);                       // d = 512

  // r[T,T] = u / -14.4269504 ; value lives in thread 255's lf register
  if (t == Tn - 1) out[blk] = lf * -0.0693147181f;
#undef STEP
}

// One block per batch element: KL term, gt transition count, soft transition count.
__global__ __launch_bounds__(256) void stats_kernel(
    const float* __restrict__ pred, const float* __restrict__ gt,
    const float* __restrict__ mu, const float* __restrict__ lv,
    const float* __restrict__ ptc, float* __restrict__ ws) {
  const int b = blockIdx.x;
  const int t = threadIdx.x;
  __shared__ float red[256];
  __shared__ float gtr_sh;

  // KL: -0.5 * sum_L (1 + lv - mu^2 - exp(lv)), free bits, relu
  float v = 0.0f;
  if (t < 128) {
    const float m = mu[b * 128 + t];
    const float l = lv[b * 128 + t];
    v = 1.0f + l - m * m - __expf(l);
  }
  red[t] = v; __syncthreads();
  for (int s = 128; s > 0; s >>= 1) { if (t < s) red[t] += red[t + s]; __syncthreads(); }
  if (t == 0) {
    const float klb = -0.5f * red[0];
    ws[512 + b] = fmaxf(klb - 0.5f, 0.0f);
  }
  __syncthreads();

  // gt_trans: sum |gt[b,t+1,2] - gt[b,t,2]|
  float g = 0.0f;
  if (t < Tn - 1)
    g = fabsf(gt[(b * Tn + t + 1) * 3 + 2] - gt[(b * Tn + t) * 3 + 2]);
  red[t] = g; __syncthreads();
  for (int s = 128; s > 0; s >>= 1) { if (t < s) red[t] += red[t + s]; __syncthreads(); }
  if (t == 0) gtr_sh = red[0];
  __syncthreads();
  const float gtr = gtr_sh;

  // soft transitions of pred touch channel: sigmoid((p-0.5)*10) diffs
  float p = 0.0f;
  if (t < Tn - 1) {
    const float z0 = (pred[(b * Tn + t) * 3 + 2]     - 0.5f) * 10.0f;
    const float z1 = (pred[(b * Tn + t + 1) * 3 + 2] - 0.5f) * 10.0f;
    const float s0 = 1.0f / (1.0f + __expf(-z0));
    const float s1 = 1.0f / (1.0f + __expf(-z1));
    p = fabsf(s1 - s0);
  }
  red[t] = p; __syncthreads();
  for (int s = 128; s > 0; s >>= 1) { if (t < s) red[t] += red[t + s]; __syncthreads(); }
  if (t == 0) {
    const float pts = red[0];
    const float d1 = ptc[b] - gtr;
    ws[640 + b] = d1 * d1;        // aux per-b
    const float d2 = pts - gtr;
    ws[768 + b] = d2 * d2;        // trans_reg per-b
  }
}

// Single block: reduce the 7 per-b arrays and emit (total, nag, kl, aux, trans_reg).
__global__ __launch_bounds__(128) void final_kernel(
    const float* __restrict__ ws, float* __restrict__ out) {
  const int t = threadIdx.x;   // 128 threads
  __shared__ float red[128];
  float sums[7];
  #pragma unroll
  for (int q = 0; q < 7; ++q) {
    red[t] = ws[q * 128 + t];
    __syncthreads();
    for (int s = 64; s > 0; s >>= 1) { if (t < s) red[t] += red[t + s]; __syncthreads(); }
    if (t == 0) sums[q] = red[0];
    __syncthreads();
  }
  if (t == 0) {
    const float inv = 1.0f / 128.0f;
    const float sim   = (sums[0] + sums[1]) * inv;
    const float dgen  = sums[2] * inv;
    const float dreal = sums[3] * inv;
    const float nag   = sim + fabsf(dgen - dreal);
    const float kl    = sums[4] * inv;
    const float aux   = sums[5] * inv;
    const float trans = sums[6] * inv;
    const float total = nag + 1.0f * kl + 0.1f * aux + 0.5f * trans;
    out[0] = total;
    out[1] = nag;
    out[2] = kl;
    out[3] = aux;
    out[4] = trans;
  }
}

extern "C" void kernel_launch(void* const* d_in, const int* in_sizes, int n_in,
                              void* d_out, int out_size, void* d_ws, size_t ws_size,
                              hipStream_t stream) {
  const float* pred = (const float*)d_in[0];   // (128,256,3)
  const float* gt   = (const float*)d_in[1];   // (128,256,3)
  const float* mu   = (const float*)d_in[2];   // (128,128)
  const float* lv   = (const float*)d_in[3];   // (128,128)
  const float* ptc  = (const float*)d_in[4];   // (128,1)
  const int*   pg   = (const int*)d_in[5];     // (128,)
  const int*   pr   = (const int*)d_in[6];     // (128,)
  float* ws  = (float*)d_ws;   // [0..511] sdtw, [512..639] kl, [640..767] aux, [768..895] trans
  float* out = (float*)d_out;  // 5 floats

  sdtw_kernel<<<512, 256, 0, stream>>>(pred, gt, pg, pr, ws);
  stats_kernel<<<128, 256, 0, stream>>>(pred, gt, mu, lv, ptc, ws);
  final_kernel<<<1, 128, 0, stream>>>(ws, out);
}

// Round 4
// 97.820 us; speedup vs baseline: 1.5176x; 1.1402x over previous
//
#include <hip/hip_runtime.h>

#define Tn 256
// Recurrence carried as u = -(10*log2e) * r  (r = DTW partial cost).
// softmin: u_new = max3(u) + log2(1 + 2^(med-max) + 2^(min-max)) - 14.4269504*cost
// cost = 0.6*om^2*dl1 folded as -8.65617024*om^2*dl1.
#define UBIG (-1.442695e9f)   // u-image of BIG=1e8
#define E2(v)  __builtin_amdgcn_exp2f(v)   // native v_exp_f32 (2^x)
#define LG2(v) __builtin_amdgcn_logf(v)    // native v_log_f32 (log2 x)

// Async 4-wave pipeline: wave w owns rows 64w+1..64w+64 (1 row/lane).
// up via __shfl_up within wave; dg = previous step's up (register).
// Cross-wave boundary (lane0) via LDS ring + volatile progress counters.
// Each wave runs only its band window. NO per-step __syncthreads.
__global__ __launch_bounds__(256) void sdtw_kernel(
    const float* __restrict__ pred, const float* __restrict__ gt,
    const int* __restrict__ perm_gen, const int* __restrict__ perm_real,
    float* __restrict__ out) {
  const int blk = blockIdx.x;
  const int c = blk >> 7;        // which of the 4 sdtw calls
  const int b = blk & 127;       // batch element

  const float* x;
  const float* y;
  if (c == 0)      { x = pred + b * Tn * 3; y = gt   + b * Tn * 3; }
  else if (c == 1) { x = gt   + b * Tn * 3; y = pred + b * Tn * 3; }
  else if (c == 2) { x = pred + b * Tn * 3; y = pred + perm_gen[b]  * Tn * 3; }
  else             { x = gt   + b * Tn * 3; y = gt   + perm_real[b] * Tn * 3; }

  __shared__ float ylds[Tn][3];        // y sequence, AoS
  __shared__ float rng[3][512];        // boundary ring: rng[w][d] = u[64(w+1)][d]
  __shared__ volatile int prog[4];     // producer progress (highest d published)

  const int t = threadIdx.x;
  const int w = t >> 6;
  const int lane = t & 63;
  float* rngf = (float*)&rng[0][0];

  // stage y, init ring to UBIG, init counters
  for (int k = t; k < Tn * 3; k += 256) (&ylds[0][0])[k] = y[k];
  for (int k = t; k < 3 * 512; k += 256) rngf[k] = UBIG;
  if (t < 4) prog[t] = 0;

  const float x0 = x[t * 3 + 0];
  const float x1 = x[t * 3 + 1];
  const float x2 = x[t * 3 + 2];

  const int i = t + 1;               // matrix row, 1..256
  const int lo = max(i + 1, 2 * i - 150);
  const int hi = min(i + Tn, 2 * i + 150);
  const unsigned span = (unsigned)(hi - lo);

  // per-wave band window [dstart, dend), multiples of 8 steps
  const int dstart = (w == 0) ? 2 : (w == 1) ? 66 : (w == 2) ? 130 : 233;
  const int dend   = (w == 0) ? 282 : (w == 1) ? 386 : (w == 2) ? 450 : 513;
  const bool wlt3 = (w != 3);

  int vcj = dstart - t - 3;          // becomes j-1 = d-t-2 after first ++
  int vdl = dstart - 1 - lo;         // becomes d - lo after first ++

  __syncthreads();                   // the ONLY block-wide barrier

  float lf = UBIG;                   // u[i][d-1] (own row, previous diagonal)
  float dgv;                         // u[i-1][d-2] = previous step's up
  if (w > 0) {
    const int need0 = dstart - 2;
    while (prog[w - 1] < need0) __builtin_amdgcn_s_sleep(2);
    __asm__ volatile("" ::: "memory");
    const float r0 = rngf[(w - 1) * 512 + dstart - 2];
    dgv = (lane == 0) ? r0 : UBIG;
  } else {
    dgv = (lane == 0) ? 0.0f : UBIG;   // r[0][0]=0 feeds cell (1,1) at d=2
  }

  for (int dbase = dstart; dbase < dend; dbase += 8) {
    // fetch 8 boundary values (up for lane0 at steps dbase..dbase+7)
    float bb[8];
    if (w > 0) {
      const int need = dbase + 6;
      while (prog[w - 1] < need) __builtin_amdgcn_s_sleep(2);
      __asm__ volatile("" ::: "memory");
      #pragma unroll
      for (int k = 0; k < 8; ++k) bb[k] = rngf[(w - 1) * 512 + dbase - 1 + k];
    } else {
      #pragma unroll
      for (int k = 0; k < 8; ++k) bb[k] = UBIG;  // row 0: r[0][j>=1] = BIG
    }

    #pragma unroll
    for (int k = 0; k < 8; ++k) {
      vcj += 1; vdl += 1;
      const int cj = vcj & 255;
      const float yy0 = ylds[cj][0];
      const float yy1 = ylds[cj][1];
      const float yy2 = ylds[cj][2];
      const float dl1 = fabsf(x0 - yy0) + fabsf(x1 - yy1) + fabsf(x2 - yy2);
      const float ex  = E2(dl1 * -1.44269504f);
      const float om  = 1.0f - ex;

      float upv = __shfl_up(lf, 1);
      if (lane == 0) upv = bb[k];

      const float mx = fmaxf(fmaxf(upv, lf), dgv);
      const float md = __builtin_amdgcn_fmed3f(upv, lf, dgv);
      const float mn = fminf(fminf(upv, lf), dgv);
      const float s  = 1.0f + E2(md - mx) + E2(mn - mx);
      float un = fmaf(om * om * dl1, -8.65617024f, mx) + LG2(s);
      un = ((unsigned)vdl <= span) ? un : UBIG;

      if (wlt3 && lane == 63) rngf[w * 512 + dbase + k] = un;  // publish boundary
      dgv = upv;
      lf = un;
    }

    // publish progress: ring writes drained before counter update
    __asm__ volatile("s_waitcnt lgkmcnt(0)" ::: "memory");
    if (wlt3 && lane == 0) prog[w] = dbase + 7;
  }

  // release any lagging consumer reading past our window (values are UBIG-init)
  __asm__ volatile("s_waitcnt lgkmcnt(0)" ::: "memory");
  if (wlt3 && lane == 0) prog[w] = 0x7fffffff;

  // u[256][512] is lane 63 of wave 3's lf after its last step (d=512)
  if (t == 255) out[blk] = lf * -0.0693147181f;
}

// One block per batch element: KL term, gt transition count, soft transition count.
__global__ __launch_bounds__(256) void stats_kernel(
    const float* __restrict__ pred, const float* __restrict__ gt,
    const float* __restrict__ mu, const float* __restrict__ lv,
    const float* __restrict__ ptc, float* __restrict__ ws) {
  const int b = blockIdx.x;
  const int t = threadIdx.x;
  __shared__ float red[256];
  __shared__ float gtr_sh;

  // KL: -0.5 * sum_L (1 + lv - mu^2 - exp(lv)), free bits, relu
  float v = 0.0f;
  if (t < 128) {
    const float m = mu[b * 128 + t];
    const float l = lv[b * 128 + t];
    v = 1.0f + l - m * m - __expf(l);
  }
  red[t] = v; __syncthreads();
  for (int s = 128; s > 0; s >>= 1) { if (t < s) red[t] += red[t + s]; __syncthreads(); }
  if (t == 0) {
    const float klb = -0.5f * red[0];
    ws[512 + b] = fmaxf(klb - 0.5f, 0.0f);
  }
  __syncthreads();

  // gt_trans: sum |gt[b,t+1,2] - gt[b,t,2]|
  float g = 0.0f;
  if (t < Tn - 1)
    g = fabsf(gt[(b * Tn + t + 1) * 3 + 2] - gt[(b * Tn + t) * 3 + 2]);
  red[t] = g; __syncthreads();
  for (int s = 128; s > 0; s >>= 1) { if (t < s) red[t] += red[t + s]; __syncthreads(); }
  if (t == 0) gtr_sh = red[0];
  __syncthreads();
  const float gtr = gtr_sh;

  // soft transitions of pred touch channel: sigmoid((p-0.5)*10) diffs
  float p = 0.0f;
  if (t < Tn - 1) {
    const float z0 = (pred[(b * Tn + t) * 3 + 2]     - 0.5f) * 10.0f;
    const float z1 = (pred[(b * Tn + t + 1) * 3 + 2] - 0.5f) * 10.0f;
    const float s0 = 1.0f / (1.0f + __expf(-z0));
    const float s1 = 1.0f / (1.0f + __expf(-z1));
    p = fabsf(s1 - s0);
  }
  red[t] = p; __syncthreads();
  for (int s = 128; s > 0; s >>= 1) { if (t < s) red[t] += red[t + s]; __syncthreads(); }
  if (t == 0) {
    const float pts = red[0];
    const float d1 = ptc[b] - gtr;
    ws[640 + b] = d1 * d1;        // aux per-b
    const float d2 = pts - gtr;
    ws[768 + b] = d2 * d2;        // trans_reg per-b
  }
}

// Single block: reduce the 7 per-b arrays and emit (total, nag, kl, aux, trans_reg).
__global__ __launch_bounds__(128) void final_kernel(
    const float* __restrict__ ws, float* __restrict__ out) {
  const int t = threadIdx.x;   // 128 threads
  __shared__ float red[128];
  float sums[7];
  #pragma unroll
  for (int q = 0; q < 7; ++q) {
    red[t] = ws[q * 128 + t];
    __syncthreads();
    for (int s = 64; s > 0; s >>= 1) { if (t < s) red[t] += red[t + s]; __syncthreads(); }
    if (t == 0) sums[q] = red[0];
    __syncthreads();
  }
  if (t == 0) {
    const float inv = 1.0f / 128.0f;
    const float sim   = (sums[0] + sums[1]) * inv;
    const float dgen  = sums[2] * inv;
    const float dreal = sums[3] * inv;
    const float nag   = sim + fabsf(dgen - dreal);
    const float kl    = sums[4] * inv;
    const float aux   = sums[5] * inv;
    const float trans = sums[6] * inv;
    const float total = nag + 1.0f * kl + 0.1f * aux + 0.5f * trans;
    out[0] = total;
    out[1] = nag;
    out[2] = kl;
    out[3] = aux;
    out[4] = trans;
  }
}

extern "C" void kernel_launch(void* const* d_in, const int* in_sizes, int n_in,
                              void* d_out, int out_size, void* d_ws, size_t ws_size,
                              hipStream_t stream) {
  const float* pred = (const float*)d_in[0];   // (128,256,3)
  const float* gt   = (const float*)d_in[1];   // (128,256,3)
  const float* mu   = (const float*)d_in[2];   // (128,128)
  const float* lv   = (const float*)d_in[3];   // (128,128)
  const float* ptc  = (const float*)d_in[4];   // (128,1)
  const int*   pg   = (const int*)d_in[5];     // (128,)
  const int*   pr   = (const int*)d_in[6];     // (128,)
  float* ws  = (float*)d_ws;   // [0..511] sdtw, [512..639] kl, [640..767] aux, [768..895] trans
  float* out = (float*)d_out;  // 5 floats

  sdtw_kernel<<<512, 256, 0, stream>>>(pred, gt, pg, pr, ws);
  stats_kernel<<<128, 256, 0, stream>>>(pred, gt, mu, lv, ptc, ws);
  final_kernel<<<1, 128, 0, stream>>>(ws, out);
}

// Round 5
// 91.458 us; speedup vs baseline: 1.6232x; 1.0696x over previous
//
#include <hip/hip_runtime.h>

#define Tn 256
// Recurrence carried as u = -(10*log2e) * r  (r = DTW partial cost).
// softmin: u_new = max3(u) + log2(1 + 2^(med-max) + 2^(min-max)) - 14.4269504*cost
// cost = 0.6*om^2*dl1 folded as -8.65617024*om^2*dl1.
#define UBIG (-1.442695e9f)   // u-image of BIG=1e8
#define E2(v)  __builtin_amdgcn_exp2f(v)   // native v_exp_f32 (2^x)
#define LG2(v) __builtin_amdgcn_logf(v)    // native v_log_f32 (log2 x)

// Async 4-wave pipeline: wave w owns rows 64w+1..64w+64 (1 row/lane).
// up via DPP wave_shr1 (lane0 <- boundary via the DPP 'old' operand).
// Cross-wave boundary via LDS ring + volatile progress counters.
// Blocks 512..639 run the (independent) stats pass instead.
__global__ __launch_bounds__(256) void sdtw_kernel(
    const float* __restrict__ pred, const float* __restrict__ gt,
    const float* __restrict__ mu, const float* __restrict__ lv,
    const float* __restrict__ ptc,
    const int* __restrict__ perm_gen, const int* __restrict__ perm_real,
    float* __restrict__ ws) {
  __shared__ float ylds[Tn][3];        // y sequence, AoS
  __shared__ float rng[3][512];        // boundary ring: rng[w][d] = u[64(w+1)][d]
  __shared__ volatile int prog[4];     // producer progress (highest d published)
  __shared__ float red[256];           // stats-path reduction buffer
  __shared__ float gtr_sh;

  const int t = threadIdx.x;

  if (blockIdx.x >= 512) {             // ---------- stats path ----------
    const int b = blockIdx.x - 512;

    // KL: -0.5 * sum_L (1 + lv - mu^2 - exp(lv)), free bits, relu
    float v = 0.0f;
    if (t < 128) {
      const float m = mu[b * 128 + t];
      const float l = lv[b * 128 + t];
      v = 1.0f + l - m * m - __expf(l);
    }
    red[t] = v; __syncthreads();
    for (int s = 128; s > 0; s >>= 1) { if (t < s) red[t] += red[t + s]; __syncthreads(); }
    if (t == 0) ws[512 + b] = fmaxf(-0.5f * red[0] - 0.5f, 0.0f);
    __syncthreads();

    // gt_trans: sum |gt[b,t+1,2] - gt[b,t,2]|
    float g = 0.0f;
    if (t < Tn - 1)
      g = fabsf(gt[(b * Tn + t + 1) * 3 + 2] - gt[(b * Tn + t) * 3 + 2]);
    red[t] = g; __syncthreads();
    for (int s = 128; s > 0; s >>= 1) { if (t < s) red[t] += red[t + s]; __syncthreads(); }
    if (t == 0) gtr_sh = red[0];
    __syncthreads();
    const float gtr = gtr_sh;

    // soft transitions of pred touch channel
    float p = 0.0f;
    if (t < Tn - 1) {
      const float z0 = (pred[(b * Tn + t) * 3 + 2]     - 0.5f) * 10.0f;
      const float z1 = (pred[(b * Tn + t + 1) * 3 + 2] - 0.5f) * 10.0f;
      const float s0 = 1.0f / (1.0f + __expf(-z0));
      const float s1 = 1.0f / (1.0f + __expf(-z1));
      p = fabsf(s1 - s0);
    }
    red[t] = p; __syncthreads();
    for (int s = 128; s > 0; s >>= 1) { if (t < s) red[t] += red[t + s]; __syncthreads(); }
    if (t == 0) {
      const float pts = red[0];
      const float d1 = ptc[b] - gtr;
      ws[640 + b] = d1 * d1;        // aux per-b
      const float d2 = pts - gtr;
      ws[768 + b] = d2 * d2;        // trans_reg per-b
    }
    return;
  }

  // ---------- sdtw path ----------
  const int blk = blockIdx.x;
  const int c = blk >> 7;        // which of the 4 sdtw calls
  const int b = blk & 127;       // batch element

  const float* x;
  const float* y;
  if (c == 0)      { x = pred + b * Tn * 3; y = gt   + b * Tn * 3; }
  else if (c == 1) { x = gt   + b * Tn * 3; y = pred + b * Tn * 3; }
  else if (c == 2) { x = pred + b * Tn * 3; y = pred + perm_gen[b]  * Tn * 3; }
  else             { x = gt   + b * Tn * 3; y = gt   + perm_real[b] * Tn * 3; }

  const int w = t >> 6;
  const int lane = t & 63;
  float* rngf = (float*)&rng[0][0];

  // stage y, init ring to UBIG, init counters
  for (int k = t; k < Tn * 3; k += 256) (&ylds[0][0])[k] = y[k];
  for (int k = t; k < 3 * 512; k += 256) rngf[k] = UBIG;
  if (t < 4) prog[t] = 0;

  const float x0 = x[t * 3 + 0];
  const float x1 = x[t * 3 + 1];
  const float x2 = x[t * 3 + 2];

  const int i = t + 1;               // matrix row, 1..256
  const int lo = max(i + 1, 2 * i - 150);
  const int hi = min(i + Tn, 2 * i + 150);
  const unsigned span = (unsigned)(hi - lo);

  // per-wave band window [dstart, dend), multiples of 8 steps
  const int dstart = (w == 0) ? 2 : (w == 1) ? 66 : (w == 2) ? 130 : 233;
  const int dend   = (w == 0) ? 282 : (w == 1) ? 386 : (w == 2) ? 450 : 513;
  const bool wlt3 = (w != 3);

  int vcj = dstart - t - 3;          // becomes j-1 = d-t-2 after first ++
  int vdl = dstart - 1 - lo;         // becomes d - lo after first ++

  __syncthreads();                   // the ONLY block-wide barrier

  float lf = UBIG;                   // u[i][d-1] (own row, previous diagonal)
  float dgv;                         // u[i-1][d-2] = previous step's up
  if (w > 0) {
    const int need0 = dstart - 2;
    while (prog[w - 1] < need0) __builtin_amdgcn_s_sleep(1);
    __asm__ volatile("" ::: "memory");
    const float r0 = rngf[(w - 1) * 512 + dstart - 2];
    dgv = (lane == 0) ? r0 : UBIG;
  } else {
    dgv = (lane == 0) ? 0.0f : UBIG;   // r[0][0]=0 feeds cell (1,1) at d=2
  }

  for (int dbase = dstart; dbase < dend; dbase += 8) {
    // fetch 8 boundary values (up for lane0 at steps dbase..dbase+7)
    float bb[8];
    if (w > 0) {
      const int need = dbase + 6;
      while (prog[w - 1] < need) __builtin_amdgcn_s_sleep(1);
      __asm__ volatile("" ::: "memory");
      #pragma unroll
      for (int k = 0; k < 8; ++k) bb[k] = rngf[(w - 1) * 512 + dbase - 1 + k];
    } else {
      #pragma unroll
      for (int k = 0; k < 8; ++k) bb[k] = UBIG;  // row 0: r[0][j>=1] = BIG
    }

    #pragma unroll
    for (int k = 0; k < 8; ++k) {
      vcj += 1; vdl += 1;
      const int cj = vcj & 255;
      const float yy0 = ylds[cj][0];
      const float yy1 = ylds[cj][1];
      const float yy2 = ylds[cj][2];
      const float dl1 = fabsf(x0 - yy0) + fabsf(x1 - yy1) + fabsf(x2 - yy2);
      const float ex  = E2(dl1 * -1.44269504f);
      const float om  = 1.0f - ex;

      // upv[lane] = lf[lane-1]; lane0 <- bb[k] via DPP 'old' operand
      const float upv = __int_as_float(__builtin_amdgcn_update_dpp(
          __float_as_int(bb[k]), __float_as_int(lf),
          0x138 /*wave_shr:1*/, 0xf, 0xf, false));

      const float mx = fmaxf(fmaxf(upv, lf), dgv);
      const float md = __builtin_amdgcn_fmed3f(upv, lf, dgv);
      const float mn = fminf(fminf(upv, lf), dgv);
      const float s  = 1.0f + E2(md - mx) + E2(mn - mx);
      float un = fmaf(om * om * dl1, -8.65617024f, mx) + LG2(s);
      un = ((unsigned)vdl <= span) ? un : UBIG;

      if (wlt3 && lane == 63) rngf[w * 512 + dbase + k] = un;  // publish boundary
      dgv = upv;
      lf = un;
    }

    // publish progress: ring writes drained before counter update
    __asm__ volatile("s_waitcnt lgkmcnt(0)" ::: "memory");
    if (wlt3 && lane == 0) prog[w] = dbase + 7;
  }

  // release any lagging consumer reading past our window (values are UBIG-init)
  __asm__ volatile("s_waitcnt lgkmcnt(0)" ::: "memory");
  if (wlt3 && lane == 0) prog[w] = 0x7fffffff;

  // u[256][512] is lane 63 of wave 3's lf after its last step (d=512)
  if (t == 255) ws[blk] = lf * -0.0693147181f;
}

// Single block: reduce the 7 per-b arrays and emit (total, nag, kl, aux, trans_reg).
__global__ __launch_bounds__(128) void final_kernel(
    const float* __restrict__ ws, float* __restrict__ out) {
  const int t = threadIdx.x;   // 128 threads
  __shared__ float red[128];
  float sums[7];
  #pragma unroll
  for (int q = 0; q < 7; ++q) {
    red[t] = ws[q * 128 + t];
    __syncthreads();
    for (int s = 64; s > 0; s >>= 1) { if (t < s) red[t] += red[t + s]; __syncthreads(); }
    if (t == 0) sums[q] = red[0];
    __syncthreads();
  }
  if (t == 0) {
    const float inv = 1.0f / 128.0f;
    const float sim   = (sums[0] + sums[1]) * inv;
    const float dgen  = sums[2] * inv;
    const float dreal = sums[3] * inv;
    const float nag   = sim + fabsf(dgen - dreal);
    const float kl    = sums[4] * inv;
    const float aux   = sums[5] * inv;
    const float trans = sums[6] * inv;
    const float total = nag + 1.0f * kl + 0.1f * aux + 0.5f * trans;
    out[0] = total;
    out[1] = nag;
    out[2] = kl;
    out[3] = aux;
    out[4] = trans;
  }
}

extern "C" void kernel_launch(void* const* d_in, const int* in_sizes, int n_in,
                              void* d_out, int out_size, void* d_ws, size_t ws_size,
                              hipStream_t stream) {
  const float* pred = (const float*)d_in[0];   // (128,256,3)
  const float* gt   = (const float*)d_in[1];   // (128,256,3)
  const float* mu   = (const float*)d_in[2];   // (128,128)
  const float* lv   = (const float*)d_in[3];   // (128,128)
  const float* ptc  = (const float*)d_in[4];   // (128,1)
  const int*   pg   = (const int*)d_in[5];     // (128,)
  const int*   pr   = (const int*)d_in[6];     // (128,)
  float* ws  = (float*)d_ws;   // [0..511] sdtw, [512..639] kl, [640..767] aux, [768..895] trans
  float* out = (float*)d_out;  // 5 floats

  sdtw_kernel<<<640, 256, 0, stream>>>(pred, gt, mu, lv, ptc, pg, pr, ws);
  final_kernel<<<1, 128, 0, stream>>>(ws, out);
}

// Round 7
// 85.507 us; speedup vs baseline: 1.7362x; 1.0696x over previous
//
#include <hip/hip_runtime.h>

#define Tn 256
// Recurrence carried as u = -(10*log2e) * r  (r = DTW partial cost).
// softmin: u_new = max3(u) + log2(1 + 2^(med-max) + 2^(min-max)) - 14.4269504*cost
// cost = 0.6*om^2*dl1 pre-folded as cost_u = -8.65617024*om^2*dl1 (data-only).
#define UBIG (-1.442695e9f)   // u-image of BIG=1e8
#define E2(v)  __builtin_amdgcn_exp2f(v)   // native v_exp_f32 (2^x)
#define LG2(v) __builtin_amdgcn_logf(v)    // native v_log_f32 (log2 x)

// Async 4-wave pipeline: wave w owns rows 64w+1..64w+64 (1 row/lane).
// up via DPP wave_shr1 (lane0 <- boundary via the DPP 'old' operand).
// Cross-wave boundary via LDS ring + volatile progress counters.
// Per 8-step chunk: prologue hoists ALL LDS reads + cost math; the serial
// core is pure-register. Ring writes batched once per chunk.
// Blocks 512..639 run the (independent) stats pass instead.
__global__ __launch_bounds__(256) void sdtw_kernel(
    const float* __restrict__ pred, const float* __restrict__ gt,
    const float* __restrict__ mu, const float* __restrict__ lv,
    const float* __restrict__ ptc,
    const int* __restrict__ perm_gen, const int* __restrict__ perm_real,
    float* __restrict__ ws) {
  __shared__ float ylds[Tn][3];        // y sequence, AoS
  __shared__ float rng[3][512];        // boundary ring: rng[w][d] = u[64(w+1)][d]
  __shared__ volatile int prog[4];     // producer progress (highest d published)
  __shared__ float red[256];           // stats-path reduction buffer
  __shared__ float gtr_sh;

  const int t = threadIdx.x;

  if (blockIdx.x >= 512) {             // ---------- stats path ----------
    const int b = blockIdx.x - 512;

    // KL: -0.5 * sum_L (1 + lv - mu^2 - exp(lv)), free bits, relu
    float v = 0.0f;
    if (t < 128) {
      const float m = mu[b * 128 + t];
      const float l = lv[b * 128 + t];
      v = 1.0f + l - m * m - __expf(l);
    }
    red[t] = v; __syncthreads();
    for (int s = 128; s > 0; s >>= 1) { if (t < s) red[t] += red[t + s]; __syncthreads(); }
    if (t == 0) ws[512 + b] = fmaxf(-0.5f * red[0] - 0.5f, 0.0f);
    __syncthreads();

    // gt_trans: sum |gt[b,t+1,2] - gt[b,t,2]|
    float g = 0.0f;
    if (t < Tn - 1)
      g = fabsf(gt[(b * Tn + t + 1) * 3 + 2] - gt[(b * Tn + t) * 3 + 2]);
    red[t] = g; __syncthreads();
    for (int s = 128; s > 0; s >>= 1) { if (t < s) red[t] += red[t + s]; __syncthreads(); }
    if (t == 0) gtr_sh = red[0];
    __syncthreads();
    const float gtr = gtr_sh;

    // soft transitions of pred touch channel
    float p = 0.0f;
    if (t < Tn - 1) {
      const float z0 = (pred[(b * Tn + t) * 3 + 2]     - 0.5f) * 10.0f;
      const float z1 = (pred[(b * Tn + t + 1) * 3 + 2] - 0.5f) * 10.0f;
      const float s0 = 1.0f / (1.0f + __expf(-z0));
      const float s1 = 1.0f / (1.0f + __expf(-z1));
      p = fabsf(s1 - s0);
    }
    red[t] = p; __syncthreads();
    for (int s = 128; s > 0; s >>= 1) { if (t < s) red[t] += red[t + s]; __syncthreads(); }
    if (t == 0) {
      const float pts = red[0];
      const float d1 = ptc[b] - gtr;
      ws[640 + b] = d1 * d1;        // aux per-b
      const float d2 = pts - gtr;
      ws[768 + b] = d2 * d2;        // trans_reg per-b
    }
    return;
  }

  // ---------- sdtw path ----------
  const int blk = blockIdx.x;
  const int c = blk >> 7;        // which of the 4 sdtw calls
  const int b = blk & 127;       // batch element

  const float* x;
  const float* y;
  if (c == 0)      { x = pred + b * Tn * 3; y = gt   + b * Tn * 3; }
  else if (c == 1) { x = gt   + b * Tn * 3; y = pred + b * Tn * 3; }
  else if (c == 2) { x = pred + b * Tn * 3; y = pred + perm_gen[b]  * Tn * 3; }
  else             { x = gt   + b * Tn * 3; y = gt   + perm_real[b] * Tn * 3; }

  const int w = t >> 6;
  const int lane = t & 63;
  float* rngf = (float*)&rng[0][0];

  // producers feed the pipeline: prioritize upstream waves
  // (s_setprio arg must be a literal constant -> wave-uniform branch ladder)
  if (w == 0)      __builtin_amdgcn_s_setprio(3);
  else if (w == 1) __builtin_amdgcn_s_setprio(2);
  else if (w == 2) __builtin_amdgcn_s_setprio(1);
  // w == 3 stays at default priority 0

  // stage y, init ring to UBIG, init counters
  for (int k = t; k < Tn * 3; k += 256) (&ylds[0][0])[k] = y[k];
  for (int k = t; k < 3 * 512; k += 256) rngf[k] = UBIG;
  if (t < 4) prog[t] = 0;

  const float x0 = x[t * 3 + 0];
  const float x1 = x[t * 3 + 1];
  const float x2 = x[t * 3 + 2];

  const int i = t + 1;               // matrix row, 1..256
  const int lo = max(i + 1, 2 * i - 150);
  const int hi = min(i + Tn, 2 * i + 150);
  const unsigned span = (unsigned)(hi - lo);

  // per-wave band window [dstart, dend), multiples of 8 steps
  const int dstart = (w == 0) ? 2 : (w == 1) ? 66 : (w == 2) ? 130 : 233;
  const int dend   = (w == 0) ? 282 : (w == 1) ? 386 : (w == 2) ? 450 : 513;
  const bool wlt3 = (w != 3);

  int cjb = dstart - t - 2;          // y index j-1 for step k=0 of the chunk
  int vdb = dstart - lo;             // d - lo for step k=0 of the chunk

  __syncthreads();                   // the ONLY block-wide barrier

  float lf = UBIG;                   // u[i][d-1] (own row, previous diagonal)
  float dgv;                         // u[i-1][d-2] = previous step's up
  if (w > 0) {
    const int need0 = dstart - 2;
    while (prog[w - 1] < need0) __builtin_amdgcn_s_sleep(1);
    __asm__ volatile("" ::: "memory");
    const float r0 = rngf[(w - 1) * 512 + dstart - 2];
    dgv = (lane == 0) ? r0 : UBIG;
  } else {
    dgv = (lane == 0) ? 0.0f : UBIG;   // r[0][0]=0 feeds cell (1,1) at d=2
  }

  for (int dbase = dstart; dbase < dend; dbase += 8) {
    // ---- prologue: ALL LDS reads + data-only cost math for 8 steps ----
    float bb[8];
    if (w > 0) {
      const int need = dbase + 6;
      while (prog[w - 1] < need) __builtin_amdgcn_s_sleep(1);
      __asm__ volatile("" ::: "memory");
      #pragma unroll
      for (int k = 0; k < 8; ++k) bb[k] = rngf[(w - 1) * 512 + dbase - 1 + k];
    } else {
      #pragma unroll
      for (int k = 0; k < 8; ++k) bb[k] = UBIG;  // row 0: r[0][j>=1] = BIG
    }

    float cost[8];
    #pragma unroll
    for (int k = 0; k < 8; ++k) {
      const int cj = (cjb + k) & 255;
      const float yy0 = ylds[cj][0];
      const float yy1 = ylds[cj][1];
      const float yy2 = ylds[cj][2];
      const float dl1 = fabsf(x0 - yy0) + fabsf(x1 - yy1) + fabsf(x2 - yy2);
      const float om  = 1.0f - E2(dl1 * -1.44269504f);
      cost[k] = om * om * dl1 * -8.65617024f;
    }

    // ---- pure-register serial core: 8 softmin steps ----
    float rr[8];
    #pragma unroll
    for (int k = 0; k < 8; ++k) {
      // upv[lane] = lf[lane-1]; lane0 <- bb[k] via DPP 'old' operand
      const float upv = __int_as_float(__builtin_amdgcn_update_dpp(
          __float_as_int(bb[k]), __float_as_int(lf),
          0x138 /*wave_shr:1*/, 0xf, 0xf, false));

      const float mx = fmaxf(fmaxf(upv, lf), dgv);
      const float md = __builtin_amdgcn_fmed3f(upv, lf, dgv);
      const float mn = fminf(fminf(upv, lf), dgv);
      const float s  = 1.0f + E2(md - mx) + E2(mn - mx);
      float un = cost[k] + mx + LG2(s);
      un = ((unsigned)(vdb + k) <= span) ? un : UBIG;
      rr[k] = un;
      dgv = upv;
      lf = un;
    }

    // ---- batched boundary publish ----
    if (wlt3 && lane == 63) {
      #pragma unroll
      for (int k = 0; k < 8; ++k) rngf[w * 512 + dbase + k] = rr[k];
    }
    __asm__ volatile("s_waitcnt lgkmcnt(0)" ::: "memory");
    if (wlt3 && lane == 0) prog[w] = dbase + 7;

    cjb += 8;
    vdb += 8;
  }

  // release any lagging consumer reading past our window (values are UBIG-init)
  __asm__ volatile("s_waitcnt lgkmcnt(0)" ::: "memory");
  if (wlt3 && lane == 0) prog[w] = 0x7fffffff;

  // u[256][512] is lane 63 of wave 3's lf after its last step (d=512)
  if (t == 255) ws[blk] = lf * -0.0693147181f;
}

// Single block: reduce the 7 per-b arrays and emit (total, nag, kl, aux, trans_reg).
__global__ __launch_bounds__(128) void final_kernel(
    const float* __restrict__ ws, float* __restrict__ out) {
  const int t = threadIdx.x;   // 128 threads
  __shared__ float red[128];
  float sums[7];
  #pragma unroll
  for (int q = 0; q < 7; ++q) {
    red[t] = ws[q * 128 + t];
    __syncthreads();
    for (int s = 64; s > 0; s >>= 1) { if (t < s) red[t] += red[t + s]; __syncthreads(); }
    if (t == 0) sums[q] = red[0];
    __syncthreads();
  }
  if (t == 0) {
    const float inv = 1.0f / 128.0f;
    const float sim   = (sums[0] + sums[1]) * inv;
    const float dgen  = sums[2] * inv;
    const float dreal = sums[3] * inv;
    const float nag   = sim + fabsf(dgen - dreal);
    const float kl    = sums[4] * inv;
    const float aux   = sums[5] * inv;
    const float trans = sums[6] * inv;
    const float total = nag + 1.0f * kl + 0.1f * aux + 0.5f * trans;
    out[0] = total;
    out[1] = nag;
    out[2] = kl;
    out[3] = aux;
    out[4] = trans;
  }
}

extern "C" void kernel_launch(void* const* d_in, const int* in_sizes, int n_in,
                              void* d_out, int out_size, void* d_ws, size_t ws_size,
                              hipStream_t stream) {
  const float* pred = (const float*)d_in[0];   // (128,256,3)
  const float* gt   = (const float*)d_in[1];   // (128,256,3)
  const float* mu   = (const float*)d_in[2];   // (128,128)
  const float* lv   = (const float*)d_in[3];   // (128,128)
  const float* ptc  = (const float*)d_in[4];   // (128,1)
  const int*   pg   = (const int*)d_in[5];     // (128,)
  const int*   pr   = (const int*)d_in[6];     // (128,)
  float* ws  = (float*)d_ws;   // [0..511] sdtw, [512..639] kl, [640..767] aux, [768..895] trans
  float* out = (float*)d_out;  // 5 floats

  sdtw_kernel<<<640, 256, 0, stream>>>(pred, gt, mu, lv, ptc, pg, pr, ws);
  final_kernel<<<1, 128, 0, stream>>>(ws, out);
}